// Round 21
// baseline (101.334 us; speedup 1.0000x reference)
//
#include <hip/hip_runtime.h>
#include <math.h>

#define NQ 12
#define DIM 4096
#define NSAMP 2048
#define NLAYERS 4

typedef _Float16 h8v __attribute__((ext_vector_type(8)));  // 8 fp16
typedef short s8v __attribute__((ext_vector_type(8)));     // 8 bf16 raw bits
typedef float f4v __attribute__((ext_vector_type(4)));

// X3 scatter: amplitude computed for pre-CNOT index o lands at b = M^{-1} o.
struct QMasks { unsigned short mv[NLAYERS][12]; };

static void cnot_masks(int l, unsigned* m) {
    int r = l % (NQ - 1) + 1;
    for (int j = 0; j < NQ; ++j) {
        unsigned v = 1u << j;
        for (int k = NQ - 1; k >= 0; --k) {
            int c = k, t = (k + r) % NQ;
            int pc = NQ - 1 - c, pt = NQ - 1 - t;
            if ((v >> pc) & 1u) v ^= (1u << pt);
        }
        m[j] = v;
    }
}

static QMasks host_masks() {
    QMasks Q{};
    for (int l = 0; l < NLAYERS; ++l) {
        unsigned m[12];
        cnot_masks(l, m);
        unsigned A[12], I[12];
        for (int k = 0; k < 12; ++k) {
            unsigned row = 0;
            for (int j = 0; j < 12; ++j) row |= ((m[j] >> k) & 1u) << j;
            A[k] = row; I[k] = 1u << k;
        }
        for (int c = 0; c < 12; ++c) {          // Gauss-Jordan over GF(2)
            int p = c; while (!((A[p] >> c) & 1u)) ++p;
            unsigned ta = A[p], ti = I[p]; A[p] = A[c]; I[p] = I[c]; A[c] = ta; I[c] = ti;
            for (int r2 = 0; r2 < 12; ++r2)
                if (r2 != c && ((A[r2] >> c) & 1u)) { A[r2] ^= A[c]; I[r2] ^= I[c]; }
        }
        for (int j = 0; j < 12; ++j) {
            unsigned colv = 0;
            for (int k = 0; k < 12; ++k) colv |= ((I[k] >> j) & 1u) << k;
            Q.mv[l][j] = (unsigned short)colv;
        }
    }
    return Q;
}

__device__ __forceinline__ unsigned short f2bf(float f) {
    unsigned u = __builtin_bit_cast(unsigned, f);
    return (unsigned short)((u + 0x7FFFu + ((u >> 16) & 1u)) >> 16);   // RNE
}
__device__ __forceinline__ float bf2f(unsigned short b) {
    unsigned u = ((unsigned)b) << 16;
    return __builtin_bit_cast(float, u);
}
__device__ __forceinline__ unsigned packh(float re, float im) {
    unsigned short rb = __builtin_bit_cast(unsigned short, (_Float16)re);
    unsigned short ib = __builtin_bit_cast(unsigned short, (_Float16)im);
    return (unsigned)rb | ((unsigned)ib << 16);
}
__device__ __forceinline__ float h2f(unsigned short h) {
    return (float)__builtin_bit_cast(_Float16, h);
}

// ---------------- Kernel A: MFMA bf16-split input GEMM + fp16 gate prep ------
// R21: 64k x 128s tiles (1024 blocks vs 2048) -> 2x MFMA per staging barrier,
// half the total staging instructions.  Math identical to verified R9-R20.
#define LDA 72
__global__ __launch_bounds__(256) void gemm_in_mfma(
        const float* __restrict__ x, const float* __restrict__ Win,
        const float* __restrict__ bin, const float* __restrict__ qw,
        unsigned short* __restrict__ h16, h8v* __restrict__ gates) {
    __shared__ unsigned short Ah[64 * LDA], Al[64 * LDA];
    __shared__ unsigned short Bh[128 * LDA], Bl[128 * LDA];
    const int tid = threadIdx.x;

    if (blockIdx.y == 16) {
        // ---- gate prep (verified R12-R20, unchanged)
        const int s = blockIdx.x;
        if (s >= 12 || tid >= 64) return;
        const int layer = s / 3, sg = s % 3;
        const int row = tid & 15, hi = tid >> 4;
        float ur[4][2][2], ui[4][2][2];
        for (int t = 0; t < 4; ++t) {
            const float* q = qw + (layer * NQ + sg * 4 + t) * 3;
            float sn, cs, sa, ca, sb, cb;
            sincosf(0.5f * q[1], &sn, &cs);
            sincosf(0.5f * (q[0] + q[2]), &sa, &ca);
            sincosf(0.5f * (q[0] - q[2]), &sb, &cb);
            ur[t][0][0] =  cs * ca; ui[t][0][0] = -cs * sa;
            ur[t][0][1] = -sn * cb; ui[t][0][1] = -sn * sb;
            ur[t][1][0] =  sn * cb; ui[t][1][0] = -sn * sb;
            ur[t][1][1] =  cs * ca; ui[t][1][1] =  cs * sa;
        }
        h8v arh, arl, aih, ail;
        for (int mm = 0; mm < 4; ++mm) {
            int m = hi * 4 + mm;
            float gr = 1.f, gi = 0.f;
            for (int t = 0; t < 4; ++t) {
                int rb = (row >> (3 - t)) & 1, cb2 = (m >> (3 - t)) & 1;
                float ar = ur[t][rb][cb2], ai = ui[t][rb][cb2];
                float nr = gr * ar - gi * ai, ni = gr * ai + gi * ar;
                gr = nr; gi = ni;
            }
            float vv[4] = {gr, -gi, gi, gr};
            _Float16 hh;
            hh = (_Float16)vv[0]; arh[2*mm]   = hh; arl[2*mm]   = (_Float16)(vv[0] - (float)hh);
            hh = (_Float16)vv[1]; arh[2*mm+1] = hh; arl[2*mm+1] = (_Float16)(vv[1] - (float)hh);
            hh = (_Float16)vv[2]; aih[2*mm]   = hh; ail[2*mm]   = (_Float16)(vv[2] - (float)hh);
            hh = (_Float16)vv[3]; aih[2*mm+1] = hh; ail[2*mm+1] = (_Float16)(vv[3] - (float)hh);
        }
        gates[(s * 4 + 0) * 64 + tid] = arh;
        gates[(s * 4 + 1) * 64 + tid] = arl;
        gates[(s * 4 + 2) * 64 + tid] = aih;
        gates[(s * 4 + 3) * 64 + tid] = ail;
        return;
    }

    const int kBase = blockIdx.x * 64;      // 64 k-rows/block (64 blocks)
    const int sBase = blockIdx.y * 128;     // 128 samples/block (16 blocks)
    const int lane = tid & 63, wc = tid >> 6;   // wave = one 32-sample group
    const int l16 = lane & 15, lg = lane >> 4;
    f4v acc[4][2] = {};

#pragma unroll 1
    for (int ch = 0; ch < 2; ++ch) {
        __syncthreads();
        // ---- A tile: Win[kBase+row][ch*64 + c], 64x64, float4 coalesced
#pragma unroll
        for (int it = 0; it < 4; ++it) {
            int idx = it * 256 + tid;
            int row = idx >> 4, c4 = (idx & 15) * 4;
            const float4 w = *(const float4*)&Win[(kBase + row) * 128 + ch * 64 + c4];
            ushort4 hi4, lo4;
            hi4.x = f2bf(w.x); lo4.x = f2bf(w.x - bf2f(hi4.x));
            hi4.y = f2bf(w.y); lo4.y = f2bf(w.y - bf2f(hi4.y));
            hi4.z = f2bf(w.z); lo4.z = f2bf(w.z - bf2f(hi4.z));
            hi4.w = f2bf(w.w); lo4.w = f2bf(w.w - bf2f(hi4.w));
            *(ushort4*)&Ah[row * LDA + c4] = hi4;
            *(ushort4*)&Al[row * LDA + c4] = lo4;
        }
        // ---- B tile: 128 srows x 64 l, coalesced on srow
#pragma unroll
        for (int it = 0; it < 32; ++it) {
            int idx = it * 256 + tid;
            int srow = idx & 127, l = idx >> 7;
            int sample = sBase + srow;
            float val = x[(sample >> 5) * 4096 + (ch * 64 + l) * 32 + (sample & 31)];
            unsigned short hv = f2bf(val);
            Bh[srow * LDA + l] = hv;
            Bl[srow * LDA + l] = f2bf(val - bf2f(hv));
        }
        __syncthreads();
#pragma unroll
        for (int kk = 0; kk < 2; ++kk) {
            s8v ah[4], al2[4], bh[2], bl[2];
#pragma unroll
            for (int r = 0; r < 4; ++r) {
                int row = r * 16 + l16;
                ah[r]  = *(s8v*)&Ah[row * LDA + kk * 32 + lg * 8];
                al2[r] = *(s8v*)&Al[row * LDA + kk * 32 + lg * 8];
            }
#pragma unroll
            for (int c = 0; c < 2; ++c) {
                int col = wc * 32 + c * 16 + l16;
                bh[c] = *(s8v*)&Bh[col * LDA + kk * 32 + lg * 8];
                bl[c] = *(s8v*)&Bl[col * LDA + kk * 32 + lg * 8];
            }
#pragma unroll
            for (int r = 0; r < 4; ++r)
#pragma unroll
                for (int c = 0; c < 2; ++c) {
                    acc[r][c] = __builtin_amdgcn_mfma_f32_16x16x32_bf16(ah[r],  bh[c], acc[r][c], 0, 0, 0);
                    acc[r][c] = __builtin_amdgcn_mfma_f32_16x16x32_bf16(ah[r],  bl[c], acc[r][c], 0, 0, 0);
                    acc[r][c] = __builtin_amdgcn_mfma_f32_16x16x32_bf16(al2[r], bh[c], acc[r][c], 0, 0, 0);
                }
        }
    }
    // ---- epilogue: D row=k, col=s; fp16 h output
#pragma unroll
    for (int r = 0; r < 4; ++r) {
        const int kg = kBase + r * 16 + lg * 4;
        const float4 b4 = *(const float4*)&bin[kg];
#pragma unroll
        for (int c = 0; c < 2; ++c) {
            const int sg2 = sBase + wc * 32 + c * 16 + l16;
            ushort4 o;
            o.x = __builtin_bit_cast(unsigned short, (_Float16)(acc[r][c][0] + b4.x + 1e-6f));
            o.y = __builtin_bit_cast(unsigned short, (_Float16)(acc[r][c][1] + b4.y + 1e-6f));
            o.z = __builtin_bit_cast(unsigned short, (_Float16)(acc[r][c][2] + b4.z + 1e-6f));
            o.w = __builtin_bit_cast(unsigned short, (_Float16)(acc[r][c][3] + b4.w + 1e-6f));
            *(ushort4*)&h16[(size_t)sg2 * 4096 + kg] = o;
        }
    }
}

// ---------------- Kernel B: MFMA qsim, 4-wave PING-PONG, stride 20 -----------
// VERBATIM from R20 (passed, 57us deterministic).  Do not touch.
#define ST 20u
#define BUFW 5120   // words per buffer: 256 cols * 20

__global__ __launch_bounds__(256, 2) void qsim_mfma(
        const unsigned short* __restrict__ h16, const h8v* __restrict__ gates,
        const float* __restrict__ Wout, const float* __restrict__ bout,
        float* __restrict__ out, QMasks Q) {
    __shared__ __align__(16) unsigned lds[2 * BUFW];   // 40960 B total
    float* red        = (float*)&lds[BUFW];            // overlays in buffer B
    float (*wred)[13] = (float(*)[13])&lds[BUFW + 8];
    float* zsh        = (float*)&lds[BUFW + 80];

    const int tid = threadIdx.x;
    const int samp = blockIdx.x;
    const int lane = tid & 63;
    const int wv = tid >> 6;
    const int l16 = tid & 15;
    const int hi = (tid >> 4) & 3;
    const f4v fz = {0.f, 0.f, 0.f, 0.f};

    // ---- load h row (fp16), norm, write canonical into buffer 0 (scaled)
    float vr[16]; float ss = 0.f;
#pragma unroll
    for (int j = 0; j < 16; ++j) {
        float f = h2f(h16[(size_t)samp * DIM + j * 256 + tid]);
        vr[j] = f; ss += f * f;
    }
#pragma unroll
    for (int o = 32; o > 0; o >>= 1) ss += __shfl_xor(ss, o);
    if (lane == 0) red[wv] = ss;
    __syncthreads();
    const float inv = 1.0f / sqrtf(red[0] + red[1] + red[2] + red[3]);
#pragma unroll
    for (int q = 0; q < 4; ++q) {
        uint4 w;
        w.x = packh(vr[4 * q + 0] * inv, 0.f);
        w.y = packh(vr[4 * q + 1] * inv, 0.f);
        w.z = packh(vr[4 * q + 2] * inv, 0.f);
        w.w = packh(vr[4 * q + 3] * inv, 0.f);
        *(uint4*)&lds[tid * ST + 4 * q] = w;
    }
    __syncthreads();

    h8v ArH, ArL, AiH, AiL;
    f4v dre0, dre1, dre2, dre3, dim0, dim1, dim2, dim3;

#define LOAD_FRAGS(S) { const h8v* gp = gates + (S) * 256 + lane;             \
    ArH = gp[0]; ArL = gp[64]; AiH = gp[128]; AiL = gp[192]; }

#define TC(RB, T, DRE, DIM) {                                                 \
    unsigned ra = (RB) + ((unsigned)(((4 * wv + (T)) << 4) | l16)) * ST       \
                + (unsigned)(hi << 2);                                        \
    h8v bf = __builtin_bit_cast(h8v, *(const uint4*)&lds[ra]);                \
    DRE = __builtin_amdgcn_mfma_f32_16x16x32_f16(ArH, bf, fz, 0, 0, 0);       \
    DRE = __builtin_amdgcn_mfma_f32_16x16x32_f16(ArL, bf, DRE, 0, 0, 0);      \
    DIM = __builtin_amdgcn_mfma_f32_16x16x32_f16(AiH, bf, fz, 0, 0, 0);       \
    DIM = __builtin_amdgcn_mfma_f32_16x16x32_f16(AiL, bf, DIM, 0, 0, 0); }

#define COMPUTE4(RB)                                                          \
    TC(RB, 0, dre0, dim0) TC(RB, 1, dre1, dim1)                               \
    TC(RB, 2, dre2, dim2) TC(RB, 3, dre3, dim3)

#define WS0(WB) {                                                             \
    unsigned wb0 = (WB) + 1280u * hi + ST * (unsigned)l16 + 4u * wv;          \
    _Pragma("unroll")                                                         \
    for (int r = 0; r < 4; ++r) {                                             \
        uint4 v;                                                              \
        v.x = packh(dre0[r], dim0[r]); v.y = packh(dre1[r], dim1[r]);         \
        v.z = packh(dre2[r], dim2[r]); v.w = packh(dre3[r], dim3[r]);         \
        *(uint4*)&lds[wb0 + 320u * r] = v; } }

#define WS1T(WB, T, DRE, DIM) {                                               \
    unsigned wa = (WB) + 320u * (unsigned)(4 * wv + (T)) + 80u * hi           \
                + (unsigned)l16;                                              \
    lds[wa]      = packh(DRE[0], DIM[0]);                                     \
    lds[wa + 20] = packh(DRE[1], DIM[1]);                                     \
    lds[wa + 40] = packh(DRE[2], DIM[2]);                                     \
    lds[wa + 60] = packh(DRE[3], DIM[3]); }
#define WS1(WB) { WS1T(WB, 0, dre0, dim0) WS1T(WB, 1, dre1, dim1)             \
                  WS1T(WB, 2, dre2, dim2) WS1T(WB, 3, dre3, dim3) }

#define X3T(WB, L, T, DRE, DIM) {                                             \
    unsigned bb = bb0;                                                        \
    if ((T) & 1) bb ^= Q.mv[L][8];                                            \
    if ((T) & 2) bb ^= Q.mv[L][9];                                            \
    unsigned b0 = bb, b1 = bb ^ Q.mv[L][0];                                   \
    unsigned b2 = bb ^ Q.mv[L][1], b3 = b1 ^ Q.mv[L][1];                      \
    lds[(WB) + (b0 & 255u) * ST + (b0 >> 8)] = packh(DRE[0], DIM[0]);         \
    lds[(WB) + (b1 & 255u) * ST + (b1 >> 8)] = packh(DRE[1], DIM[1]);         \
    lds[(WB) + (b2 & 255u) * ST + (b2 >> 8)] = packh(DRE[2], DIM[2]);         \
    lds[(WB) + (b3 & 255u) * ST + (b3 >> 8)] = packh(DRE[3], DIM[3]); }
#define WX3(WB, L) {                                                          \
    unsigned bb0 = 0;                                                         \
    if (hi & 1)  bb0 ^= Q.mv[L][2];  if (hi & 2)  bb0 ^= Q.mv[L][3];          \
    if (l16 & 1) bb0 ^= Q.mv[L][4];  if (l16 & 2) bb0 ^= Q.mv[L][5];          \
    if (l16 & 4) bb0 ^= Q.mv[L][6];  if (l16 & 8) bb0 ^= Q.mv[L][7];          \
    if (wv & 1)  bb0 ^= Q.mv[L][10]; if (wv & 2)  bb0 ^= Q.mv[L][11];         \
    X3T(WB, L, 0, dre0, dim0) X3T(WB, L, 1, dre1, dim1)                       \
    X3T(WB, L, 2, dre2, dim2) X3T(WB, L, 3, dre3, dim3) }

#define RUN_LAYER(L, A, B)                                                    \
    LOAD_FRAGS(3 * (L) + 0) COMPUTE4(A) WS0(B)    __syncthreads();            \
    LOAD_FRAGS(3 * (L) + 1) COMPUTE4(B) WS1(A)    __syncthreads();            \
    LOAD_FRAGS(3 * (L) + 2) COMPUTE4(A) WX3(B, L) __syncthreads();

    RUN_LAYER(0, 0, BUFW)
    RUN_LAYER(1, BUFW, 0)
    RUN_LAYER(2, 0, BUFW)
    RUN_LAYER(3, BUFW, 0)

    // ---- expvals from canonical buffer 0: amp a = (j<<8)|tid
    float P = 0.f;
    float z03[4] = {0.f, 0.f, 0.f, 0.f};
#pragma unroll
    for (int g = 0; g < 4; ++g) {
        uint4 u4 = *(const uint4*)&lds[tid * ST + 4 * g];
        unsigned uu[4] = {u4.x, u4.y, u4.z, u4.w};
#pragma unroll
        for (int e = 0; e < 4; ++e) {
            const int j = 4 * g + e;
            float re = h2f((unsigned short)(uu[e] & 0xFFFFu));
            float im = h2f((unsigned short)(uu[e] >> 16));
            float pr = re * re + im * im;
            P += pr;
#pragma unroll
            for (int i = 0; i < 4; ++i)
                z03[i] += ((j >> (3 - i)) & 1) ? -pr : pr;
        }
    }
    float zv[12];
#pragma unroll
    for (int i = 0; i < 4; ++i) zv[i] = z03[i];
#pragma unroll
    for (int i = 4; i < 12; ++i)
        zv[i] = ((tid >> (11 - i)) & 1) ? -P : P;
    __syncthreads();   // buffer-0 reads done before overlay writes below
#pragma unroll
    for (int i = 0; i < 12; ++i) {
        float z = zv[i];
#pragma unroll
        for (int o = 32; o > 0; o >>= 1) z += __shfl_xor(z, o);
        if (lane == 0) wred[wv][i] = z;
    }
    {
        float v = P;
#pragma unroll
        for (int o = 32; o > 0; o >>= 1) v += __shfl_xor(v, o);
        if (lane == 0) wred[wv][12] = v;
    }
    __syncthreads();
    if (tid < 13)
        zsh[tid] = wred[0][tid] + wred[1][tid] + wred[2][tid] + wred[3][tid];
    __syncthreads();

    if (tid < 96) {
        const float invP = 1.0f / zsh[12];   // residual fp16 drift correction
        float acc = bout[tid];
#pragma unroll
        for (int i = 0; i < 12; ++i) acc += zsh[i] * invP * Wout[tid * 12 + i];
        int b = samp >> 5, m = samp & 31;
        out[b * (96 * 32) + tid * 32 + m] = acc;
    }
}

extern "C" void kernel_launch(void* const* d_in, const int* in_sizes, int n_in,
                              void* d_out, int out_size, void* d_ws, size_t ws_size,
                              hipStream_t stream) {
    const float* x    = (const float*)d_in[0];
    const float* Win  = (const float*)d_in[1];
    const float* bin  = (const float*)d_in[2];
    const float* qw   = (const float*)d_in[3];
    const float* Wout = (const float*)d_in[4];
    const float* bout = (const float*)d_in[5];
    unsigned short* h16 = (unsigned short*)d_ws;                       // 16 MB
    h8v* gates = (h8v*)((char*)d_ws + (size_t)NSAMP * DIM * 2);        // 48 KB

    QMasks Q = host_masks();

    gemm_in_mfma<<<dim3(64, 17), 256, 0, stream>>>(x, Win, bin, qw, h16, gates);
    qsim_mfma<<<dim3(NSAMP), 256, 0, stream>>>(h16, gates, Wout, bout,
                                               (float*)d_out, Q);
}

// Round 22
// 74.867 us; speedup vs baseline: 1.3535x; 1.3535x over previous
//
#include <hip/hip_runtime.h>
#include <math.h>

#define NQ 12
#define DIM 4096
#define NSAMP 2048
#define NLAYERS 4

typedef _Float16 h8v __attribute__((ext_vector_type(8)));  // 8 fp16
typedef short s8v __attribute__((ext_vector_type(8)));     // 8 bf16 raw bits
typedef float f4v __attribute__((ext_vector_type(4)));

// X3 scatter: amplitude computed for pre-CNOT index o lands at b = M^{-1} o.
struct QMasks { unsigned short mv[NLAYERS][12]; };

static void cnot_masks(int l, unsigned* m) {
    int r = l % (NQ - 1) + 1;
    for (int j = 0; j < NQ; ++j) {
        unsigned v = 1u << j;
        for (int k = NQ - 1; k >= 0; --k) {
            int c = k, t = (k + r) % NQ;
            int pc = NQ - 1 - c, pt = NQ - 1 - t;
            if ((v >> pc) & 1u) v ^= (1u << pt);
        }
        m[j] = v;
    }
}

static QMasks host_masks() {
    QMasks Q{};
    for (int l = 0; l < NLAYERS; ++l) {
        unsigned m[12];
        cnot_masks(l, m);
        unsigned A[12], I[12];
        for (int k = 0; k < 12; ++k) {
            unsigned row = 0;
            for (int j = 0; j < 12; ++j) row |= ((m[j] >> k) & 1u) << j;
            A[k] = row; I[k] = 1u << k;
        }
        for (int c = 0; c < 12; ++c) {          // Gauss-Jordan over GF(2)
            int p = c; while (!((A[p] >> c) & 1u)) ++p;
            unsigned ta = A[p], ti = I[p]; A[p] = A[c]; I[p] = I[c]; A[c] = ta; I[c] = ti;
            for (int r2 = 0; r2 < 12; ++r2)
                if (r2 != c && ((A[r2] >> c) & 1u)) { A[r2] ^= A[c]; I[r2] ^= I[c]; }
        }
        for (int j = 0; j < 12; ++j) {
            unsigned colv = 0;
            for (int k = 0; k < 12; ++k) colv |= ((I[k] >> j) & 1u) << k;
            Q.mv[l][j] = (unsigned short)colv;
        }
    }
    return Q;
}

__device__ __forceinline__ unsigned short f2bf(float f) {
    unsigned u = __builtin_bit_cast(unsigned, f);
    return (unsigned short)((u + 0x7FFFu + ((u >> 16) & 1u)) >> 16);   // RNE
}
__device__ __forceinline__ float bf2f(unsigned short b) {
    unsigned u = ((unsigned)b) << 16;
    return __builtin_bit_cast(float, u);
}
__device__ __forceinline__ unsigned packh(float re, float im) {
    unsigned short rb = __builtin_bit_cast(unsigned short, (_Float16)re);
    unsigned short ib = __builtin_bit_cast(unsigned short, (_Float16)im);
    return (unsigned)rb | ((unsigned)ib << 16);
}
__device__ __forceinline__ float h2f(unsigned short h) {
    return (float)__builtin_bit_cast(_Float16, h);
}

// ---------------- Kernel A: MFMA bf16-split input GEMM + fp16 gate prep ------
// R20 shape (64x64 tiles, verified R9-R20) + R22 coalesced epilogue: D staged
// through idle Bh LDS as [s][k], then 16-B contiguous global writes.
#define LDA 72
__global__ __launch_bounds__(256) void gemm_in_mfma(
        const float* __restrict__ x, const float* __restrict__ Win,
        const float* __restrict__ bin, const float* __restrict__ qw,
        unsigned short* __restrict__ h16, h8v* __restrict__ gates) {
    __shared__ unsigned short Ah[64 * LDA], Al[64 * LDA];
    __shared__ unsigned short Bh[64 * LDA], Bl[64 * LDA];
    const int tid = threadIdx.x;

    if (blockIdx.y == 32) {
        // ---- gate prep (verified R12-R20, unchanged)
        const int s = blockIdx.x;
        if (s >= 12 || tid >= 64) return;
        const int layer = s / 3, sg = s % 3;
        const int row = tid & 15, hi = tid >> 4;
        float ur[4][2][2], ui[4][2][2];
        for (int t = 0; t < 4; ++t) {
            const float* q = qw + (layer * NQ + sg * 4 + t) * 3;
            float sn, cs, sa, ca, sb, cb;
            sincosf(0.5f * q[1], &sn, &cs);
            sincosf(0.5f * (q[0] + q[2]), &sa, &ca);
            sincosf(0.5f * (q[0] - q[2]), &sb, &cb);
            ur[t][0][0] =  cs * ca; ui[t][0][0] = -cs * sa;
            ur[t][0][1] = -sn * cb; ui[t][0][1] = -sn * sb;
            ur[t][1][0] =  sn * cb; ui[t][1][0] = -sn * sb;
            ur[t][1][1] =  cs * ca; ui[t][1][1] =  cs * sa;
        }
        h8v arh, arl, aih, ail;
        for (int mm = 0; mm < 4; ++mm) {
            int m = hi * 4 + mm;
            float gr = 1.f, gi = 0.f;
            for (int t = 0; t < 4; ++t) {
                int rb = (row >> (3 - t)) & 1, cb2 = (m >> (3 - t)) & 1;
                float ar = ur[t][rb][cb2], ai = ui[t][rb][cb2];
                float nr = gr * ar - gi * ai, ni = gr * ai + gi * ar;
                gr = nr; gi = ni;
            }
            float vv[4] = {gr, -gi, gi, gr};
            _Float16 hh;
            hh = (_Float16)vv[0]; arh[2*mm]   = hh; arl[2*mm]   = (_Float16)(vv[0] - (float)hh);
            hh = (_Float16)vv[1]; arh[2*mm+1] = hh; arl[2*mm+1] = (_Float16)(vv[1] - (float)hh);
            hh = (_Float16)vv[2]; aih[2*mm]   = hh; ail[2*mm]   = (_Float16)(vv[2] - (float)hh);
            hh = (_Float16)vv[3]; aih[2*mm+1] = hh; ail[2*mm+1] = (_Float16)(vv[3] - (float)hh);
        }
        gates[(s * 4 + 0) * 64 + tid] = arh;
        gates[(s * 4 + 1) * 64 + tid] = arl;
        gates[(s * 4 + 2) * 64 + tid] = aih;
        gates[(s * 4 + 3) * 64 + tid] = ail;
        return;
    }

    const int kBase = blockIdx.x * 64;
    const int sBase = blockIdx.y * 64;
    const int lane = tid & 63, wid = tid >> 6;
    const int wr = wid >> 1, wc = wid & 1;
    const int l16 = lane & 15, lg = lane >> 4;
    const int xbase = (sBase >> 5) * 4096;
    f4v acc[2][2] = {};

#pragma unroll 1
    for (int ch = 0; ch < 2; ++ch) {
        __syncthreads();
#pragma unroll
        for (int it = 0; it < 4; ++it) {
            int idx = it * 256 + tid;
            int row = idx >> 4, c4 = (idx & 15) * 4;
            const float4 w = *(const float4*)&Win[(kBase + row) * 128 + ch * 64 + c4];
            ushort4 hi4, lo4;
            hi4.x = f2bf(w.x); lo4.x = f2bf(w.x - bf2f(hi4.x));
            hi4.y = f2bf(w.y); lo4.y = f2bf(w.y - bf2f(hi4.y));
            hi4.z = f2bf(w.z); lo4.z = f2bf(w.z - bf2f(hi4.z));
            hi4.w = f2bf(w.w); lo4.w = f2bf(w.w - bf2f(hi4.w));
            *(ushort4*)&Ah[row * LDA + c4] = hi4;
            *(ushort4*)&Al[row * LDA + c4] = lo4;
        }
#pragma unroll
        for (int it = 0; it < 16; ++it) {
            int idx = it * 256 + tid;
            int srow = idx & 63, l = idx >> 6;
            float val = x[xbase + (srow >> 5) * 4096 + (ch * 64 + l) * 32 + (srow & 31)];
            unsigned short hv = f2bf(val);
            Bh[srow * LDA + l] = hv;
            Bl[srow * LDA + l] = f2bf(val - bf2f(hv));
        }
        __syncthreads();
#pragma unroll
        for (int kk = 0; kk < 2; ++kk) {
            s8v ah[2], al2[2], bh[2], bl[2];
#pragma unroll
            for (int r = 0; r < 2; ++r) {
                int row = wr * 32 + r * 16 + l16;
                ah[r]  = *(s8v*)&Ah[row * LDA + kk * 32 + lg * 8];
                al2[r] = *(s8v*)&Al[row * LDA + kk * 32 + lg * 8];
            }
#pragma unroll
            for (int c = 0; c < 2; ++c) {
                int col = wc * 32 + c * 16 + l16;
                bh[c] = *(s8v*)&Bh[col * LDA + kk * 32 + lg * 8];
                bl[c] = *(s8v*)&Bl[col * LDA + kk * 32 + lg * 8];
            }
#pragma unroll
            for (int r = 0; r < 2; ++r)
#pragma unroll
                for (int c = 0; c < 2; ++c) {
                    acc[r][c] = __builtin_amdgcn_mfma_f32_16x16x32_bf16(ah[r],  bh[c], acc[r][c], 0, 0, 0);
                    acc[r][c] = __builtin_amdgcn_mfma_f32_16x16x32_bf16(ah[r],  bl[c], acc[r][c], 0, 0, 0);
                    acc[r][c] = __builtin_amdgcn_mfma_f32_16x16x32_bf16(al2[r], bh[c], acc[r][c], 0, 0, 0);
                }
        }
    }
    // ---- R22 epilogue: stage D into Bh as [s_local][k_local], then coalesced
    __syncthreads();   // all frag reads of Bh/Bl complete
#pragma unroll
    for (int r = 0; r < 2; ++r) {
        const int kg = wr * 32 + r * 16 + lg * 4;            // local k
        const float4 b4 = *(const float4*)&bin[kBase + kg];
#pragma unroll
        for (int c = 0; c < 2; ++c) {
            const int sl = wc * 32 + c * 16 + l16;           // local s
            ushort4 o;
            o.x = __builtin_bit_cast(unsigned short, (_Float16)(acc[r][c][0] + b4.x + 1e-6f));
            o.y = __builtin_bit_cast(unsigned short, (_Float16)(acc[r][c][1] + b4.y + 1e-6f));
            o.z = __builtin_bit_cast(unsigned short, (_Float16)(acc[r][c][2] + b4.z + 1e-6f));
            o.w = __builtin_bit_cast(unsigned short, (_Float16)(acc[r][c][3] + b4.w + 1e-6f));
            *(ushort4*)&Bh[sl * LDA + kg] = o;
        }
    }
    __syncthreads();
    // cooperative write: 8 threads cover one s-row's 128 B (k 0..63), uint4
#pragma unroll
    for (int it = 0; it < 2; ++it) {
        const int sl = it * 32 + (tid >> 3);
        const int kseg = (tid & 7) * 8;
        uint4 v = *(const uint4*)&Bh[sl * LDA + kseg];
        *(uint4*)&h16[(size_t)(sBase + sl) * 4096 + kBase + kseg] = v;
    }
}

// ---------------- Kernel B: MFMA qsim, 4-wave PING-PONG, stride 20 -----------
// VERBATIM from R20 (passed, 57us deterministic).  Do not touch.
#define ST 20u
#define BUFW 5120   // words per buffer: 256 cols * 20

__global__ __launch_bounds__(256, 2) void qsim_mfma(
        const unsigned short* __restrict__ h16, const h8v* __restrict__ gates,
        const float* __restrict__ Wout, const float* __restrict__ bout,
        float* __restrict__ out, QMasks Q) {
    __shared__ __align__(16) unsigned lds[2 * BUFW];   // 40960 B total
    float* red        = (float*)&lds[BUFW];            // overlays in buffer B
    float (*wred)[13] = (float(*)[13])&lds[BUFW + 8];
    float* zsh        = (float*)&lds[BUFW + 80];

    const int tid = threadIdx.x;
    const int samp = blockIdx.x;
    const int lane = tid & 63;
    const int wv = tid >> 6;
    const int l16 = tid & 15;
    const int hi = (tid >> 4) & 3;
    const f4v fz = {0.f, 0.f, 0.f, 0.f};

    // ---- load h row (fp16), norm, write canonical into buffer 0 (scaled)
    float vr[16]; float ss = 0.f;
#pragma unroll
    for (int j = 0; j < 16; ++j) {
        float f = h2f(h16[(size_t)samp * DIM + j * 256 + tid]);
        vr[j] = f; ss += f * f;
    }
#pragma unroll
    for (int o = 32; o > 0; o >>= 1) ss += __shfl_xor(ss, o);
    if (lane == 0) red[wv] = ss;
    __syncthreads();
    const float inv = 1.0f / sqrtf(red[0] + red[1] + red[2] + red[3]);
#pragma unroll
    for (int q = 0; q < 4; ++q) {
        uint4 w;
        w.x = packh(vr[4 * q + 0] * inv, 0.f);
        w.y = packh(vr[4 * q + 1] * inv, 0.f);
        w.z = packh(vr[4 * q + 2] * inv, 0.f);
        w.w = packh(vr[4 * q + 3] * inv, 0.f);
        *(uint4*)&lds[tid * ST + 4 * q] = w;
    }
    __syncthreads();

    h8v ArH, ArL, AiH, AiL;
    f4v dre0, dre1, dre2, dre3, dim0, dim1, dim2, dim3;

#define LOAD_FRAGS(S) { const h8v* gp = gates + (S) * 256 + lane;             \
    ArH = gp[0]; ArL = gp[64]; AiH = gp[128]; AiL = gp[192]; }

#define TC(RB, T, DRE, DIM) {                                                 \
    unsigned ra = (RB) + ((unsigned)(((4 * wv + (T)) << 4) | l16)) * ST       \
                + (unsigned)(hi << 2);                                        \
    h8v bf = __builtin_bit_cast(h8v, *(const uint4*)&lds[ra]);                \
    DRE = __builtin_amdgcn_mfma_f32_16x16x32_f16(ArH, bf, fz, 0, 0, 0);       \
    DRE = __builtin_amdgcn_mfma_f32_16x16x32_f16(ArL, bf, DRE, 0, 0, 0);      \
    DIM = __builtin_amdgcn_mfma_f32_16x16x32_f16(AiH, bf, fz, 0, 0, 0);       \
    DIM = __builtin_amdgcn_mfma_f32_16x16x32_f16(AiL, bf, DIM, 0, 0, 0); }

#define COMPUTE4(RB)                                                          \
    TC(RB, 0, dre0, dim0) TC(RB, 1, dre1, dim1)                               \
    TC(RB, 2, dre2, dim2) TC(RB, 3, dre3, dim3)

#define WS0(WB) {                                                             \
    unsigned wb0 = (WB) + 1280u * hi + ST * (unsigned)l16 + 4u * wv;          \
    _Pragma("unroll")                                                         \
    for (int r = 0; r < 4; ++r) {                                             \
        uint4 v;                                                              \
        v.x = packh(dre0[r], dim0[r]); v.y = packh(dre1[r], dim1[r]);         \
        v.z = packh(dre2[r], dim2[r]); v.w = packh(dre3[r], dim3[r]);         \
        *(uint4*)&lds[wb0 + 320u * r] = v; } }

#define WS1T(WB, T, DRE, DIM) {                                               \
    unsigned wa = (WB) + 320u * (unsigned)(4 * wv + (T)) + 80u * hi           \
                + (unsigned)l16;                                              \
    lds[wa]      = packh(DRE[0], DIM[0]);                                     \
    lds[wa + 20] = packh(DRE[1], DIM[1]);                                     \
    lds[wa + 40] = packh(DRE[2], DIM[2]);                                     \
    lds[wa + 60] = packh(DRE[3], DIM[3]); }
#define WS1(WB) { WS1T(WB, 0, dre0, dim0) WS1T(WB, 1, dre1, dim1)             \
                  WS1T(WB, 2, dre2, dim2) WS1T(WB, 3, dre3, dim3) }

#define X3T(WB, L, T, DRE, DIM) {                                             \
    unsigned bb = bb0;                                                        \
    if ((T) & 1) bb ^= Q.mv[L][8];                                            \
    if ((T) & 2) bb ^= Q.mv[L][9];                                            \
    unsigned b0 = bb, b1 = bb ^ Q.mv[L][0];                                   \
    unsigned b2 = bb ^ Q.mv[L][1], b3 = b1 ^ Q.mv[L][1];                      \
    lds[(WB) + (b0 & 255u) * ST + (b0 >> 8)] = packh(DRE[0], DIM[0]);         \
    lds[(WB) + (b1 & 255u) * ST + (b1 >> 8)] = packh(DRE[1], DIM[1]);         \
    lds[(WB) + (b2 & 255u) * ST + (b2 >> 8)] = packh(DRE[2], DIM[2]);         \
    lds[(WB) + (b3 & 255u) * ST + (b3 >> 8)] = packh(DRE[3], DIM[3]); }
#define WX3(WB, L) {                                                          \
    unsigned bb0 = 0;                                                         \
    if (hi & 1)  bb0 ^= Q.mv[L][2];  if (hi & 2)  bb0 ^= Q.mv[L][3];          \
    if (l16 & 1) bb0 ^= Q.mv[L][4];  if (l16 & 2) bb0 ^= Q.mv[L][5];          \
    if (l16 & 4) bb0 ^= Q.mv[L][6];  if (l16 & 8) bb0 ^= Q.mv[L][7];          \
    if (wv & 1)  bb0 ^= Q.mv[L][10]; if (wv & 2)  bb0 ^= Q.mv[L][11];         \
    X3T(WB, L, 0, dre0, dim0) X3T(WB, L, 1, dre1, dim1)                       \
    X3T(WB, L, 2, dre2, dim2) X3T(WB, L, 3, dre3, dim3) }

#define RUN_LAYER(L, A, B)                                                    \
    LOAD_FRAGS(3 * (L) + 0) COMPUTE4(A) WS0(B)    __syncthreads();            \
    LOAD_FRAGS(3 * (L) + 1) COMPUTE4(B) WS1(A)    __syncthreads();            \
    LOAD_FRAGS(3 * (L) + 2) COMPUTE4(A) WX3(B, L) __syncthreads();

    RUN_LAYER(0, 0, BUFW)
    RUN_LAYER(1, BUFW, 0)
    RUN_LAYER(2, 0, BUFW)
    RUN_LAYER(3, BUFW, 0)

    // ---- expvals from canonical buffer 0: amp a = (j<<8)|tid
    float P = 0.f;
    float z03[4] = {0.f, 0.f, 0.f, 0.f};
#pragma unroll
    for (int g = 0; g < 4; ++g) {
        uint4 u4 = *(const uint4*)&lds[tid * ST + 4 * g];
        unsigned uu[4] = {u4.x, u4.y, u4.z, u4.w};
#pragma unroll
        for (int e = 0; e < 4; ++e) {
            const int j = 4 * g + e;
            float re = h2f((unsigned short)(uu[e] & 0xFFFFu));
            float im = h2f((unsigned short)(uu[e] >> 16));
            float pr = re * re + im * im;
            P += pr;
#pragma unroll
            for (int i = 0; i < 4; ++i)
                z03[i] += ((j >> (3 - i)) & 1) ? -pr : pr;
        }
    }
    float zv[12];
#pragma unroll
    for (int i = 0; i < 4; ++i) zv[i] = z03[i];
#pragma unroll
    for (int i = 4; i < 12; ++i)
        zv[i] = ((tid >> (11 - i)) & 1) ? -P : P;
    __syncthreads();   // buffer-0 reads done before overlay writes below
#pragma unroll
    for (int i = 0; i < 12; ++i) {
        float z = zv[i];
#pragma unroll
        for (int o = 32; o > 0; o >>= 1) z += __shfl_xor(z, o);
        if (lane == 0) wred[wv][i] = z;
    }
    {
        float v = P;
#pragma unroll
        for (int o = 32; o > 0; o >>= 1) v += __shfl_xor(v, o);
        if (lane == 0) wred[wv][12] = v;
    }
    __syncthreads();
    if (tid < 13)
        zsh[tid] = wred[0][tid] + wred[1][tid] + wred[2][tid] + wred[3][tid];
    __syncthreads();

    if (tid < 96) {
        const float invP = 1.0f / zsh[12];   // residual fp16 drift correction
        float acc = bout[tid];
#pragma unroll
        for (int i = 0; i < 12; ++i) acc += zsh[i] * invP * Wout[tid * 12 + i];
        int b = samp >> 5, m = samp & 31;
        out[b * (96 * 32) + tid * 32 + m] = acc;
    }
}

extern "C" void kernel_launch(void* const* d_in, const int* in_sizes, int n_in,
                              void* d_out, int out_size, void* d_ws, size_t ws_size,
                              hipStream_t stream) {
    const float* x    = (const float*)d_in[0];
    const float* Win  = (const float*)d_in[1];
    const float* bin  = (const float*)d_in[2];
    const float* qw   = (const float*)d_in[3];
    const float* Wout = (const float*)d_in[4];
    const float* bout = (const float*)d_in[5];
    unsigned short* h16 = (unsigned short*)d_ws;                       // 16 MB
    h8v* gates = (h8v*)((char*)d_ws + (size_t)NSAMP * DIM * 2);        // 48 KB

    QMasks Q = host_masks();

    gemm_in_mfma<<<dim3(64, 33), 256, 0, stream>>>(x, Win, bin, qw, h16, gates);
    qsim_mfma<<<dim3(NSAMP), 256, 0, stream>>>(h16, gates, Wout, bout,
                                               (float*)d_out, Q);
}